// Round 4
// baseline (157.273 us; speedup 1.0000x reference)
//
#include <hip/hip_runtime.h>

#define HW   16384
#define CH   256
#define WD   128
#define BB   4
#define NPTS 4

typedef _Float16 half8 __attribute__((ext_vector_type(8)));
typedef _Float16 half4 __attribute__((ext_vector_type(4)));
typedef float    f32x4 __attribute__((ext_vector_type(4)));

// ---- workspace layout (bytes) ----
#define WS_XT    0ull            // _Float16 [65536][256]  32 MB  (x transposed, per-pixel)
#define WS_QH    33554432ull     // _Float16 [65536][256]  32 MB  (Qh = A x + cvec)
#define WS_W     67108864ull     // _Float16 [65536][256]  32 MB  (w = sum_n attn_n x_j)
#define WS_WQK   100663296ull    // _Float16 [256][256]    128 KB (A = Wk^T Wq)
#define WS_WV    100794368ull    // _Float16 [256][256]    128 KB
#define WS_WOQ   100925440ull    // float    [256][8]      8 KB
#define WS_BOF   100933632ull    // float    [8]
#define WS_CVEC  100934656ull    // float    [256]         (Wk^T bq)
#define WS_DVEC  100935680ull    // float    [256]         (bk^T Wq -> Wq^T bk)
#define WS_SC    100936704ull    // float    [1]           (bq.bk)
#define WS_SVEC  100936768ull    // float    [65536]       256 KB (s_p per pixel)
#define WS_ASUM  101198912ull    // float    [65536]       256 KB (sum_n attn)
#define WS_IDX   101461056ull    // int      [4][4][16384] 1 MB

// ---------- weight prep: A=Wk^T Wq fp16, cvec, Wv fp16, woq/bof, dvec, sconst ----------
__global__ void k_wprep(const float* __restrict__ Wq, const float* __restrict__ bq,
                        const float* __restrict__ Wk, const float* __restrict__ bk,
                        const float* __restrict__ Wv, const float* __restrict__ bv,
                        const float* __restrict__ Wo, const float* __restrict__ bo,
                        _Float16* __restrict__ wqk16, float* __restrict__ cvec,
                        _Float16* __restrict__ wv16, float* __restrict__ woq,
                        float* __restrict__ bof, float* __restrict__ dvec,
                        float* __restrict__ scst) {
    int bid = blockIdx.x, t = threadIdx.x;
    if (bid < 256) {                 // A[i][t] = sum_o Wk[o][i]*Wq[o][t]
        int i = bid;
        float s = 0.f;
        for (int o = 0; o < 256; o++) s += Wk[o * 256 + i] * Wq[o * 256 + t];
        wqk16[i * 256 + t] = (_Float16)s;
        if (t == 0) {
            float cs = 0.f;
            for (int o = 0; o < 256; o++) cs += Wk[o * 256 + i] * bq[o];
            cvec[i] = cs;
        }
    } else if (bid < 512) {          // Wv -> fp16
        int r = bid - 256;
        wv16[r * 256 + t] = (_Float16)Wv[r * 256 + t];
    } else if (bid < 520) {          // fused offset weights (fp32, discontinuous path)
        int j = bid - 512;
        float s = 0.f;
        for (int o = 0; o < 256; o++) s += Wo[j * 256 + o] * Wq[o * 256 + t];
        woq[t * 8 + j] = s;
        if (t == 0) {
            float tt = bo[j];
            for (int o = 0; o < 256; o++) tt += Wo[j * 256 + o] * bq[o];
            bof[j] = tt;
        }
    } else {                         // dvec[t] = sum_o bk[o]*Wq[o][t]; sconst = bq.bk
        float s = 0.f;
        for (int o = 0; o < 256; o++) s += bk[o] * Wq[o * 256 + t];
        dvec[t] = s;
        if (t == 0) {
            float sc = 0.f;
            for (int o = 0; o < 256; o++) sc += bq[o] * bk[o];
            scst[0] = sc;
        }
    }
}

// ---------- fused: x -> xt fp16, offsets -> idx (pure f32), s_p ----------
__launch_bounds__(256)
__global__ void k_prep(const float* __restrict__ x, const float* __restrict__ woq,
                       const float* __restrict__ bof, const float* __restrict__ dvec,
                       const float* __restrict__ scst,
                       _Float16* __restrict__ xt, int* __restrict__ idxb,
                       float* __restrict__ svec) {
    __shared__ float    wl[256 * 8];
    __shared__ float    dl[256];
    __shared__ float    bl8[8];
    __shared__ _Float16 tile[64][280];      // pitch 560B: b128 writes spread over all 8 slots
    __shared__ float    red[4][64][8];
    __shared__ float    reds[4][64];

    int t = threadIdx.x;
    for (int i = t; i < 256 * 8; i += 256) wl[i] = woq[i];
    dl[t] = dvec[t];
    if (t < 8) bl8[t] = bof[t];
    __syncthreads();

    int b = blockIdx.y;
    int p0 = blockIdx.x * 64;
    int pl = t & 63, cg = t >> 6;
    const float* xb = x + (size_t)b * CH * HW + p0 + pl;

    float acc[8];
    #pragma unroll
    for (int j = 0; j < 8; j++) acc[j] = 0.f;
    float accs = 0.f;

    for (int i0 = 0; i0 < 64; i0 += 8) {
        half8 hv;
        #pragma unroll
        for (int i = 0; i < 8; i++) {
            int c = cg * 64 + i0 + i;
            float xv = xb[(size_t)c * HW];
            hv[i] = (_Float16)xv;
            accs += dl[c] * xv;
            #pragma unroll
            for (int j = 0; j < 8; j++) acc[j] += wl[c * 8 + j] * xv;
        }
        *(half8*)(&tile[pl][cg * 64 + i0]) = hv;
    }
    #pragma unroll
    for (int j = 0; j < 8; j++) red[cg][pl][j] = acc[j];
    reds[cg][pl] = accs;
    __syncthreads();

    {
        int n = cg, p = p0 + pl;
        float sw_ = bl8[2 * n]     + red[0][pl][2 * n]     + red[1][pl][2 * n]
                                   + red[2][pl][2 * n]     + red[3][pl][2 * n];
        float sh_ = bl8[2 * n + 1] + red[0][pl][2 * n + 1] + red[1][pl][2 * n + 1]
                                   + red[2][pl][2 * n + 1] + red[3][pl][2 * n + 1];
        int h = p >> 7, w = p & 127;
        float rw = fminf(fmaxf((float)w + sw_, 0.f), 127.f);
        float rh = fminf(fmaxf((float)h + sh_, 0.f), 127.f);
        idxb[(b * NPTS + n) * HW + p] = ((int)rh) * WD + (int)rw;
        if (cg == 0)
            svec[b * HW + p] = reds[0][pl] + reds[1][pl] + reds[2][pl] + reds[3][pl] + scst[0];
    }

    {
        int row = t >> 2;
        size_t gbase = ((size_t)(b * HW + p0 + row)) * 256;
        #pragma unroll
        for (int s = 0; s < 8; s++) {
            int seg = (t & 3) + s * 4;
            *(uint4*)(xt + gbase + seg * 8) = *(const uint4*)(&tile[row][seg * 8]);
        }
    }
}

// ---------- GEMM1: qh[p][n] = sum_k A[n][k] xt[p][k] + cvec[n] ----------
__launch_bounds__(256)
__global__ void k_gemm1(const _Float16* __restrict__ xt, const _Float16* __restrict__ wqk16,
                        const float* __restrict__ cvec, _Float16* __restrict__ qh) {
    __shared__ _Float16 As[128 * 32];
    __shared__ _Float16 Bs[128 * 32];
    int tid = threadIdx.x;
    int bid = blockIdx.x;
    int logical = (bid & 7) * 128 + (bid >> 3);   // 1024 = 8*128, bijective
    int nt = logical & 1, mt = logical >> 1;
    int m0 = mt * 128, n0 = nt * 128;

    int lane = tid & 63, wid = tid >> 6;
    int wr = wid >> 1, wc = wid & 1;
    int g = lane >> 4, r = lane & 15;
    int ar = tid >> 2, aseg = tid & 3;
    int sw = aseg ^ ((ar >> 1) & 3);

    f32x4 acc[4][4] = {};

    for (int kt = 0; kt < 8; kt++) {
        int k0 = kt * 32;
        uint4 a0 = *(const uint4*)(xt    + ((size_t)(m0 + ar))      * 256 + k0 + aseg * 8);
        uint4 a1 = *(const uint4*)(xt    + ((size_t)(m0 + 64 + ar)) * 256 + k0 + aseg * 8);
        uint4 b0 = *(const uint4*)(wqk16 + ((size_t)(n0 + ar))      * 256 + k0 + aseg * 8);
        uint4 b1 = *(const uint4*)(wqk16 + ((size_t)(n0 + 64 + ar)) * 256 + k0 + aseg * 8);
        __syncthreads();
        *(uint4*)(As + ar * 32 + sw * 8)        = a0;
        *(uint4*)(As + (64 + ar) * 32 + sw * 8) = a1;
        *(uint4*)(Bs + ar * 32 + sw * 8)        = b0;
        *(uint4*)(Bs + (64 + ar) * 32 + sw * 8) = b1;
        __syncthreads();

        half8 af[4], bf[4];
        #pragma unroll
        for (int mb = 0; mb < 4; mb++) {
            int row = wr * 64 + mb * 16 + r;
            int slot = g ^ ((row >> 1) & 3);
            af[mb] = *(const half8*)(As + row * 32 + slot * 8);
        }
        #pragma unroll
        for (int nb = 0; nb < 4; nb++) {
            int row = wc * 64 + nb * 16 + r;
            int slot = g ^ ((row >> 1) & 3);
            bf[nb] = *(const half8*)(Bs + row * 32 + slot * 8);
        }
        // swapped operands: D (g*4+reg) <- bf rows (n), (lane&15) <- af rows (m)
        #pragma unroll
        for (int mb = 0; mb < 4; mb++)
            #pragma unroll
            for (int nb = 0; nb < 4; nb++)
                acc[mb][nb] = __builtin_amdgcn_mfma_f32_16x16x32_f16(bf[nb], af[mb], acc[mb][nb], 0, 0, 0);
    }

    #pragma unroll
    for (int mb = 0; mb < 4; mb++) {
        int m = m0 + wr * 64 + mb * 16 + r;
        #pragma unroll
        for (int nb = 0; nb < 4; nb++) {
            int nbase = n0 + wc * 64 + nb * 16 + g * 4;
            f32x4 bb = *(const f32x4*)(cvec + nbase);
            half4 h;
            #pragma unroll
            for (int i = 0; i < 4; i++) h[i] = (_Float16)(acc[mb][nb][i] + bb[i]);
            *(half4*)(qh + (size_t)m * 256 + nbase) = h;
        }
    }
}

// ---------- gather: attn_n = Qh_p.x_j + s_p ;  w_p = sum attn_n x_j ; asum ----------
__launch_bounds__(256)
__global__ void k_attn2(const _Float16* __restrict__ xt, const _Float16* __restrict__ qh,
                        const int* __restrict__ idxb, const float* __restrict__ svec,
                        _Float16* __restrict__ w16, float* __restrict__ asum) {
    __shared__ float attn_s[64][4];
    __shared__ int   idx_s[4][64];
    int tid = threadIdx.x;
    int b = blockIdx.y;
    int p0 = blockIdx.x * 64;

    {   // phase A: thread = (pixel, n); 256-len fp16 dot in f32
        int pl = tid >> 2, n = tid & 3;
        int p = p0 + pl;
        int j = idxb[(b * NPTS + n) * HW + p];
        const half8* qrow = (const half8*)(qh + ((size_t)(b * HW + p)) * 256);
        const half8* xrow = (const half8*)(xt + ((size_t)(b * HW + j)) * 256);
        float acc = 0.f;
        #pragma unroll 8
        for (int k = 0; k < 32; k++) {
            half8 a = qrow[k], c = xrow[k];
            #pragma unroll
            for (int e = 0; e < 8; e++) acc += (float)a[e] * (float)c[e];
        }
        attn_s[pl][n] = acc + svec[b * HW + p];
        idx_s[n][pl]  = j;
    }
    __syncthreads();

    {   // phase B: wave wv owns channels [wv*64,+64); lane = pixel
        int wv = tid >> 6, lane = tid & 63;
        int p = p0 + lane;
        int cb = wv * 64;
        float o[64];
        #pragma unroll
        for (int i = 0; i < 64; i++) o[i] = 0.f;
        float asl = 0.f;
        #pragma unroll
        for (int nn = 0; nn < 4; nn++) {
            float a = attn_s[lane][nn];
            asl += a;
            const half8* xrow = (const half8*)(xt + ((size_t)(b * HW + idx_s[nn][lane])) * 256 + cb);
            #pragma unroll
            for (int j = 0; j < 8; j++) {
                half8 v8 = xrow[j];
                #pragma unroll
                for (int e = 0; e < 8; e++) o[j * 8 + e] += a * (float)v8[e];
            }
        }
        size_t wb_ = ((size_t)(b * HW + p)) * 256 + cb;
        #pragma unroll
        for (int j = 0; j < 8; j++) {
            half8 h;
            #pragma unroll
            for (int e = 0; e < 8; e++) h[e] = (_Float16)o[j * 8 + e];
            *(half8*)(w16 + wb_ + j * 8) = h;
        }
        if (wv == 0) asum[b * HW + p] = asl;
    }
}

// ---------- GEMM2: out[b][c][p] = sum_k Wv[c][k] w[m][k] + asum[m]*bv[c] ----------
__launch_bounds__(256)
__global__ void k_gemm2(const _Float16* __restrict__ w16, const _Float16* __restrict__ wv16,
                        const float* __restrict__ asum, const float* __restrict__ bv,
                        float* __restrict__ out) {
    __shared__ _Float16 As[128 * 32];
    __shared__ _Float16 Bs[128 * 32];
    int tid = threadIdx.x;
    int bid = blockIdx.x;
    int logical = (bid & 7) * 128 + (bid >> 3);
    int nt = logical & 1, mt = logical >> 1;
    int m0 = mt * 128, n0 = nt * 128;

    int lane = tid & 63, wid = tid >> 6;
    int wr = wid >> 1, wc = wid & 1;
    int g = lane >> 4, r = lane & 15;
    int ar = tid >> 2, aseg = tid & 3;
    int sw = aseg ^ ((ar >> 1) & 3);

    f32x4 acc[4][4] = {};

    for (int kt = 0; kt < 8; kt++) {
        int k0 = kt * 32;
        uint4 a0 = *(const uint4*)(w16  + ((size_t)(m0 + ar))      * 256 + k0 + aseg * 8);
        uint4 a1 = *(const uint4*)(w16  + ((size_t)(m0 + 64 + ar)) * 256 + k0 + aseg * 8);
        uint4 b0 = *(const uint4*)(wv16 + ((size_t)(n0 + ar))      * 256 + k0 + aseg * 8);
        uint4 b1 = *(const uint4*)(wv16 + ((size_t)(n0 + 64 + ar)) * 256 + k0 + aseg * 8);
        __syncthreads();
        *(uint4*)(As + ar * 32 + sw * 8)        = a0;
        *(uint4*)(As + (64 + ar) * 32 + sw * 8) = a1;
        *(uint4*)(Bs + ar * 32 + sw * 8)        = b0;
        *(uint4*)(Bs + (64 + ar) * 32 + sw * 8) = b1;
        __syncthreads();

        half8 af[4], bf[4];
        #pragma unroll
        for (int mb = 0; mb < 4; mb++) {
            int row = wr * 64 + mb * 16 + r;
            int slot = g ^ ((row >> 1) & 3);
            af[mb] = *(const half8*)(As + row * 32 + slot * 8);
        }
        #pragma unroll
        for (int nb = 0; nb < 4; nb++) {
            int row = wc * 64 + nb * 16 + r;
            int slot = g ^ ((row >> 1) & 3);
            bf[nb] = *(const half8*)(Bs + row * 32 + slot * 8);
        }
        // FIX (r3 bug): swapped operands to match epilogue mapping:
        // D (g*4+reg) <- bf rows (n=channel), (lane&15) <- af rows (m=pixel)
        #pragma unroll
        for (int mb = 0; mb < 4; mb++)
            #pragma unroll
            for (int nb = 0; nb < 4; nb++)
                acc[mb][nb] = __builtin_amdgcn_mfma_f32_16x16x32_f16(bf[nb], af[mb], acc[mb][nb], 0, 0, 0);
    }

    #pragma unroll
    for (int mb = 0; mb < 4; mb++) {
        int m = m0 + wr * 64 + mb * 16 + r;          // global pixel (b*HW + p)
        float am = asum[m];
        int bq_ = m >> 14, pl_ = m & 16383;
        float* obase = out + ((size_t)bq_ * 256) * HW + pl_;
        #pragma unroll
        for (int nb = 0; nb < 4; nb++) {
            int cb = n0 + wc * 64 + nb * 16 + g * 4;
            f32x4 bb = *(const f32x4*)(bv + cb);
            #pragma unroll
            for (int i = 0; i < 4; i++)
                obase[(size_t)(cb + i) * HW] = acc[mb][nb][i] + am * bb[i];
        }
    }
}

extern "C" void kernel_launch(void* const* d_in, const int* in_sizes, int n_in,
                              void* d_out, int out_size, void* d_ws, size_t ws_size,
                              hipStream_t stream) {
    const float* x  = (const float*)d_in[0];
    const float* Wq = (const float*)d_in[1];
    const float* bq = (const float*)d_in[2];
    const float* Wk = (const float*)d_in[3];
    const float* bk = (const float*)d_in[4];
    const float* Wv = (const float*)d_in[5];
    const float* bv = (const float*)d_in[6];
    const float* Wo = (const float*)d_in[7];
    const float* bo = (const float*)d_in[8];
    (void)in_sizes; (void)n_in; (void)out_size; (void)ws_size;

    char* ws = (char*)d_ws;
    _Float16* xt    = (_Float16*)(ws + WS_XT);
    _Float16* qh    = (_Float16*)(ws + WS_QH);
    _Float16* w16   = (_Float16*)(ws + WS_W);
    _Float16* wqk16 = (_Float16*)(ws + WS_WQK);
    _Float16* wv16  = (_Float16*)(ws + WS_WV);
    float*    woq   = (float*)(ws + WS_WOQ);
    float*    bof   = (float*)(ws + WS_BOF);
    float*    cvec  = (float*)(ws + WS_CVEC);
    float*    dvec  = (float*)(ws + WS_DVEC);
    float*    scst  = (float*)(ws + WS_SC);
    float*    svec  = (float*)(ws + WS_SVEC);
    float*    asum  = (float*)(ws + WS_ASUM);
    int*      idxb  = (int*)(ws + WS_IDX);

    k_wprep<<<521, 256, 0, stream>>>(Wq, bq, Wk, bk, Wv, bv, Wo, bo,
                                     wqk16, cvec, wv16, woq, bof, dvec, scst);
    k_prep<<<dim3(256, 4), 256, 0, stream>>>(x, woq, bof, dvec, scst, xt, idxb, svec);
    k_gemm1<<<1024, 256, 0, stream>>>(xt, wqk16, cvec, qh);
    k_attn2<<<dim3(256, 4), 256, 0, stream>>>(xt, qh, idxb, svec, w16, asum);
    k_gemm2<<<1024, 256, 0, stream>>>(w16, wv16, asum, bv, (float*)d_out);
}

// Round 5
// 115.035 us; speedup vs baseline: 1.3672x; 1.3672x over previous
//
#include <hip/hip_runtime.h>

#define HW   16384
#define CH   256
#define WD   128
#define BB   4
#define NPTS 4

typedef _Float16 half8 __attribute__((ext_vector_type(8)));
typedef _Float16 half4 __attribute__((ext_vector_type(4)));
typedef float    f32x4 __attribute__((ext_vector_type(4)));

// ---- workspace layout (bytes) ----
#define WS_XT    0ull            // _Float16 [65536][256]  32 MB  (x transposed, per-pixel)
#define WS_QH    33554432ull     // _Float16 [65536][256]  32 MB  (Qh = A x + cvec)
#define WS_W     67108864ull     // _Float16 [65536][256]  32 MB  (w = sum_n attn_n x_j)
#define WS_WQK   100663296ull    // _Float16 [256][256]    128 KB (A = Wk^T Wq)
#define WS_WV    100794368ull    // _Float16 [256][256]    128 KB
#define WS_WOQ   100925440ull    // float    [256][8]      8 KB
#define WS_BOF   100933632ull    // float    [8]
#define WS_CVEC  100934656ull    // float    [256]         (Wk^T bq)
#define WS_DVEC  100935680ull    // float    [256]         (Wq^T bk)
#define WS_SC    100936704ull    // float    [1]           (bq.bk)
#define WS_SVEC  100936768ull    // float    [65536]       256 KB (s_p per pixel)
#define WS_ASUM  101198912ull    // float    [65536]       256 KB (sum_n attn)
#define WS_IDX   101461056ull    // int      [4][4][16384] 1 MB

// ---------- weight prep: A=Wk^T Wq fp16, cvec, Wv fp16, woq/bof, dvec, sconst ----------
__global__ void k_wprep(const float* __restrict__ Wq, const float* __restrict__ bq,
                        const float* __restrict__ Wk, const float* __restrict__ bk,
                        const float* __restrict__ Wv, const float* __restrict__ bv,
                        const float* __restrict__ Wo, const float* __restrict__ bo,
                        _Float16* __restrict__ wqk16, float* __restrict__ cvec,
                        _Float16* __restrict__ wv16, float* __restrict__ woq,
                        float* __restrict__ bof, float* __restrict__ dvec,
                        float* __restrict__ scst) {
    int bid = blockIdx.x, t = threadIdx.x;
    if (bid < 256) {                 // A[i][t] = sum_o Wk[o][i]*Wq[o][t]
        int i = bid;
        float s = 0.f;
        for (int o = 0; o < 256; o++) s += Wk[o * 256 + i] * Wq[o * 256 + t];
        wqk16[i * 256 + t] = (_Float16)s;
        if (t == 0) {
            float cs = 0.f;
            for (int o = 0; o < 256; o++) cs += Wk[o * 256 + i] * bq[o];
            cvec[i] = cs;
        }
    } else if (bid < 512) {          // Wv -> fp16
        int r = bid - 256;
        wv16[r * 256 + t] = (_Float16)Wv[r * 256 + t];
    } else if (bid < 520) {          // fused offset weights (fp32, discontinuous path)
        int j = bid - 512;
        float s = 0.f;
        for (int o = 0; o < 256; o++) s += Wo[j * 256 + o] * Wq[o * 256 + t];
        woq[t * 8 + j] = s;
        if (t == 0) {
            float tt = bo[j];
            for (int o = 0; o < 256; o++) tt += Wo[j * 256 + o] * bq[o];
            bof[j] = tt;
        }
    } else {                         // dvec[t] = sum_o bk[o]*Wq[o][t]; sconst = bq.bk
        float s = 0.f;
        for (int o = 0; o < 256; o++) s += bk[o] * Wq[o * 256 + t];
        dvec[t] = s;
        if (t == 0) {
            float sc = 0.f;
            for (int o = 0; o < 256; o++) sc += bq[o] * bk[o];
            scst[0] = sc;
        }
    }
}

// ---------- fused: x -> xt fp16, offsets -> idx (pure f32), s_p ----------
__launch_bounds__(256)
__global__ void k_prep(const float* __restrict__ x, const float* __restrict__ woq,
                       const float* __restrict__ bof, const float* __restrict__ dvec,
                       const float* __restrict__ scst,
                       _Float16* __restrict__ xt, int* __restrict__ idxb,
                       float* __restrict__ svec) {
    __shared__ float    wl[256 * 8];
    __shared__ float    dl[256];
    __shared__ float    bl8[8];
    __shared__ _Float16 tile[64][280];      // pitch 560B: b128 writes spread over all 8 slots
    __shared__ float    red[4][64][8];
    __shared__ float    reds[4][64];

    int t = threadIdx.x;
    for (int i = t; i < 256 * 8; i += 256) wl[i] = woq[i];
    dl[t] = dvec[t];
    if (t < 8) bl8[t] = bof[t];
    __syncthreads();

    int b = blockIdx.y;
    int p0 = blockIdx.x * 64;
    int pl = t & 63, cg = t >> 6;
    const float* xb = x + (size_t)b * CH * HW + p0 + pl;

    float acc[8];
    #pragma unroll
    for (int j = 0; j < 8; j++) acc[j] = 0.f;
    float accs = 0.f;

    for (int i0 = 0; i0 < 64; i0 += 8) {
        half8 hv;
        #pragma unroll
        for (int i = 0; i < 8; i++) {
            int c = cg * 64 + i0 + i;
            float xv = xb[(size_t)c * HW];
            hv[i] = (_Float16)xv;
            accs += dl[c] * xv;
            #pragma unroll
            for (int j = 0; j < 8; j++) acc[j] += wl[c * 8 + j] * xv;
        }
        *(half8*)(&tile[pl][cg * 64 + i0]) = hv;
    }
    #pragma unroll
    for (int j = 0; j < 8; j++) red[cg][pl][j] = acc[j];
    reds[cg][pl] = accs;
    __syncthreads();

    {
        int n = cg, p = p0 + pl;
        float sw_ = bl8[2 * n]     + red[0][pl][2 * n]     + red[1][pl][2 * n]
                                   + red[2][pl][2 * n]     + red[3][pl][2 * n];
        float sh_ = bl8[2 * n + 1] + red[0][pl][2 * n + 1] + red[1][pl][2 * n + 1]
                                   + red[2][pl][2 * n + 1] + red[3][pl][2 * n + 1];
        int h = p >> 7, w = p & 127;
        float rw = fminf(fmaxf((float)w + sw_, 0.f), 127.f);
        float rh = fminf(fmaxf((float)h + sh_, 0.f), 127.f);
        idxb[(b * NPTS + n) * HW + p] = ((int)rh) * WD + (int)rw;
        if (cg == 0)
            svec[b * HW + p] = reds[0][pl] + reds[1][pl] + reds[2][pl] + reds[3][pl] + scst[0];
    }

    {
        int row = t >> 2;
        size_t gbase = ((size_t)(b * HW + p0 + row)) * 256;
        #pragma unroll
        for (int s = 0; s < 8; s++) {
            int seg = (t & 3) + s * 4;
            *(uint4*)(xt + gbase + seg * 8) = *(const uint4*)(&tile[row][seg * 8]);
        }
    }
}

// ---------- GEMM1: qh[p][n] = sum_k A[n][k] xt[p][k] + cvec[n] ----------
__launch_bounds__(256)
__global__ void k_gemm1(const _Float16* __restrict__ xt, const _Float16* __restrict__ wqk16,
                        const float* __restrict__ cvec, _Float16* __restrict__ qh) {
    __shared__ _Float16 As[128 * 32];
    __shared__ _Float16 Bs[128 * 32];
    int tid = threadIdx.x;
    int bid = blockIdx.x;
    int logical = (bid & 7) * 128 + (bid >> 3);   // 1024 = 8*128, bijective
    int nt = logical & 1, mt = logical >> 1;
    int m0 = mt * 128, n0 = nt * 128;

    int lane = tid & 63, wid = tid >> 6;
    int wr = wid >> 1, wc = wid & 1;
    int g = lane >> 4, r = lane & 15;
    int ar = tid >> 2, aseg = tid & 3;
    int sw = aseg ^ ((ar >> 1) & 3);

    f32x4 acc[4][4] = {};

    for (int kt = 0; kt < 8; kt++) {
        int k0 = kt * 32;
        uint4 a0 = *(const uint4*)(xt    + ((size_t)(m0 + ar))      * 256 + k0 + aseg * 8);
        uint4 a1 = *(const uint4*)(xt    + ((size_t)(m0 + 64 + ar)) * 256 + k0 + aseg * 8);
        uint4 b0 = *(const uint4*)(wqk16 + ((size_t)(n0 + ar))      * 256 + k0 + aseg * 8);
        uint4 b1 = *(const uint4*)(wqk16 + ((size_t)(n0 + 64 + ar)) * 256 + k0 + aseg * 8);
        __syncthreads();
        *(uint4*)(As + ar * 32 + sw * 8)        = a0;
        *(uint4*)(As + (64 + ar) * 32 + sw * 8) = a1;
        *(uint4*)(Bs + ar * 32 + sw * 8)        = b0;
        *(uint4*)(Bs + (64 + ar) * 32 + sw * 8) = b1;
        __syncthreads();

        half8 af[4], bf[4];
        #pragma unroll
        for (int mb = 0; mb < 4; mb++) {
            int row = wr * 64 + mb * 16 + r;
            int slot = g ^ ((row >> 1) & 3);
            af[mb] = *(const half8*)(As + row * 32 + slot * 8);
        }
        #pragma unroll
        for (int nb = 0; nb < 4; nb++) {
            int row = wc * 64 + nb * 16 + r;
            int slot = g ^ ((row >> 1) & 3);
            bf[nb] = *(const half8*)(Bs + row * 32 + slot * 8);
        }
        // swapped operands: D (g*4+reg) <- bf rows (n), (lane&15) <- af rows (m)
        #pragma unroll
        for (int mb = 0; mb < 4; mb++)
            #pragma unroll
            for (int nb = 0; nb < 4; nb++)
                acc[mb][nb] = __builtin_amdgcn_mfma_f32_16x16x32_f16(bf[nb], af[mb], acc[mb][nb], 0, 0, 0);
    }

    #pragma unroll
    for (int mb = 0; mb < 4; mb++) {
        int m = m0 + wr * 64 + mb * 16 + r;
        #pragma unroll
        for (int nb = 0; nb < 4; nb++) {
            int nbase = n0 + wc * 64 + nb * 16 + g * 4;
            f32x4 bb = *(const f32x4*)(cvec + nbase);
            half4 h;
            #pragma unroll
            for (int i = 0; i < 4; i++) h[i] = (_Float16)(acc[mb][nb][i] + bb[i]);
            *(half4*)(qh + (size_t)m * 256 + nbase) = h;
        }
    }
}

// ---------- gather (single-pass): 16 threads/pixel, x_j kept in regs ----------
// attn_n = Qh_p.x_j + s_p ; w_p = sum_n attn_n x_j ; asum_p = sum_n attn_n
// block 256 thr = 16 px; grid (HW/16 = 1024, B); XCD-chunked swizzle (1024 = 8*128)
__launch_bounds__(256)
__global__ void k_attn3(const _Float16* __restrict__ xt, const _Float16* __restrict__ qh,
                        const int* __restrict__ idxb, const float* __restrict__ svec,
                        _Float16* __restrict__ w16, float* __restrict__ asum) {
    int t = threadIdx.x;
    int px = t >> 4, seg = t & 15;
    int b = blockIdx.y;
    int bx = blockIdx.x;
    int logical = (bx & 7) * 128 + (bx >> 3);       // contiguous pixel chunk per XCD
    int p = logical * 16 + px;
    size_t m = (size_t)b * HW + p;

    // load Q segment (16 halves)
    const half8* qrow = (const half8*)(qh + m * 256 + seg * 16);
    half8 q0 = qrow[0], q1 = qrow[1];
    float sv = svec[m];

    // prefetch indices
    int jj[NPTS];
    #pragma unroll
    for (int n = 0; n < NPTS; n++) jj[n] = idxb[(b * NPTS + n) * HW + p];

    float o[16];
    #pragma unroll
    for (int e = 0; e < 16; e++) o[e] = 0.f;
    float asl = 0.f;

    #pragma unroll
    for (int n = 0; n < NPTS; n++) {
        const half8* xrow = (const half8*)(xt + ((size_t)b * HW + jj[n]) * 256 + seg * 16);
        half8 x0 = xrow[0], x1 = xrow[1];
        float d = 0.f;
        #pragma unroll
        for (int e = 0; e < 8; e++) d += (float)q0[e] * (float)x0[e];
        #pragma unroll
        for (int e = 0; e < 8; e++) d += (float)q1[e] * (float)x1[e];
        // reduce across the 16-lane pixel group
        d += __shfl_xor(d, 1);
        d += __shfl_xor(d, 2);
        d += __shfl_xor(d, 4);
        d += __shfl_xor(d, 8);
        float a = d + sv;
        asl += a;
        #pragma unroll
        for (int e = 0; e < 8; e++) o[e]     += a * (float)x0[e];
        #pragma unroll
        for (int e = 0; e < 8; e++) o[8 + e] += a * (float)x1[e];
    }

    // write w segment (two half8 = 32B contiguous per thread)
    half8 h0, h1;
    #pragma unroll
    for (int e = 0; e < 8; e++) { h0[e] = (_Float16)o[e]; h1[e] = (_Float16)o[8 + e]; }
    half8* wrow = (half8*)(w16 + m * 256 + seg * 16);
    wrow[0] = h0;
    wrow[1] = h1;
    if (seg == 0) asum[m] = asl;
}

// ---------- GEMM2: out[b][c][p] = sum_k Wv[c][k] w[m][k] + asum[m]*bv[c] ----------
__launch_bounds__(256)
__global__ void k_gemm2(const _Float16* __restrict__ w16, const _Float16* __restrict__ wv16,
                        const float* __restrict__ asum, const float* __restrict__ bv,
                        float* __restrict__ out) {
    __shared__ _Float16 As[128 * 32];
    __shared__ _Float16 Bs[128 * 32];
    int tid = threadIdx.x;
    int bid = blockIdx.x;
    int logical = (bid & 7) * 128 + (bid >> 3);
    int nt = logical & 1, mt = logical >> 1;
    int m0 = mt * 128, n0 = nt * 128;

    int lane = tid & 63, wid = tid >> 6;
    int wr = wid >> 1, wc = wid & 1;
    int g = lane >> 4, r = lane & 15;
    int ar = tid >> 2, aseg = tid & 3;
    int sw = aseg ^ ((ar >> 1) & 3);

    f32x4 acc[4][4] = {};

    for (int kt = 0; kt < 8; kt++) {
        int k0 = kt * 32;
        uint4 a0 = *(const uint4*)(w16  + ((size_t)(m0 + ar))      * 256 + k0 + aseg * 8);
        uint4 a1 = *(const uint4*)(w16  + ((size_t)(m0 + 64 + ar)) * 256 + k0 + aseg * 8);
        uint4 b0 = *(const uint4*)(wv16 + ((size_t)(n0 + ar))      * 256 + k0 + aseg * 8);
        uint4 b1 = *(const uint4*)(wv16 + ((size_t)(n0 + 64 + ar)) * 256 + k0 + aseg * 8);
        __syncthreads();
        *(uint4*)(As + ar * 32 + sw * 8)        = a0;
        *(uint4*)(As + (64 + ar) * 32 + sw * 8) = a1;
        *(uint4*)(Bs + ar * 32 + sw * 8)        = b0;
        *(uint4*)(Bs + (64 + ar) * 32 + sw * 8) = b1;
        __syncthreads();

        half8 af[4], bf[4];
        #pragma unroll
        for (int mb = 0; mb < 4; mb++) {
            int row = wr * 64 + mb * 16 + r;
            int slot = g ^ ((row >> 1) & 3);
            af[mb] = *(const half8*)(As + row * 32 + slot * 8);
        }
        #pragma unroll
        for (int nb = 0; nb < 4; nb++) {
            int row = wc * 64 + nb * 16 + r;
            int slot = g ^ ((row >> 1) & 3);
            bf[nb] = *(const half8*)(Bs + row * 32 + slot * 8);
        }
        // swapped operands: D (g*4+reg) <- bf rows (n=channel), (lane&15) <- af rows (m=pixel)
        #pragma unroll
        for (int mb = 0; mb < 4; mb++)
            #pragma unroll
            for (int nb = 0; nb < 4; nb++)
                acc[mb][nb] = __builtin_amdgcn_mfma_f32_16x16x32_f16(bf[nb], af[mb], acc[mb][nb], 0, 0, 0);
    }

    #pragma unroll
    for (int mb = 0; mb < 4; mb++) {
        int m = m0 + wr * 64 + mb * 16 + r;          // global pixel (b*HW + p)
        float am = asum[m];
        int bq_ = m >> 14, pl_ = m & 16383;
        float* obase = out + ((size_t)bq_ * 256) * HW + pl_;
        #pragma unroll
        for (int nb = 0; nb < 4; nb++) {
            int cb = n0 + wc * 64 + nb * 16 + g * 4;
            f32x4 bb = *(const f32x4*)(bv + cb);
            #pragma unroll
            for (int i = 0; i < 4; i++)
                obase[(size_t)(cb + i) * HW] = acc[mb][nb][i] + am * bb[i];
        }
    }
}

extern "C" void kernel_launch(void* const* d_in, const int* in_sizes, int n_in,
                              void* d_out, int out_size, void* d_ws, size_t ws_size,
                              hipStream_t stream) {
    const float* x  = (const float*)d_in[0];
    const float* Wq = (const float*)d_in[1];
    const float* bq = (const float*)d_in[2];
    const float* Wk = (const float*)d_in[3];
    const float* bk = (const float*)d_in[4];
    const float* Wv = (const float*)d_in[5];
    const float* bv = (const float*)d_in[6];
    const float* Wo = (const float*)d_in[7];
    const float* bo = (const float*)d_in[8];
    (void)in_sizes; (void)n_in; (void)out_size; (void)ws_size;

    char* ws = (char*)d_ws;
    _Float16* xt    = (_Float16*)(ws + WS_XT);
    _Float16* qh    = (_Float16*)(ws + WS_QH);
    _Float16* w16   = (_Float16*)(ws + WS_W);
    _Float16* wqk16 = (_Float16*)(ws + WS_WQK);
    _Float16* wv16  = (_Float16*)(ws + WS_WV);
    float*    woq   = (float*)(ws + WS_WOQ);
    float*    bof   = (float*)(ws + WS_BOF);
    float*    cvec  = (float*)(ws + WS_CVEC);
    float*    dvec  = (float*)(ws + WS_DVEC);
    float*    scst  = (float*)(ws + WS_SC);
    float*    svec  = (float*)(ws + WS_SVEC);
    float*    asum  = (float*)(ws + WS_ASUM);
    int*      idxb  = (int*)(ws + WS_IDX);

    k_wprep<<<521, 256, 0, stream>>>(Wq, bq, Wk, bk, Wv, bv, Wo, bo,
                                     wqk16, cvec, wv16, woq, bof, dvec, scst);
    k_prep<<<dim3(256, 4), 256, 0, stream>>>(x, woq, bof, dvec, scst, xt, idxb, svec);
    k_gemm1<<<1024, 256, 0, stream>>>(xt, wqk16, cvec, qh);
    k_attn3<<<dim3(1024, 4), 256, 0, stream>>>(xt, qh, idxb, svec, w16, asum);
    k_gemm2<<<1024, 256, 0, stream>>>(w16, wv16, asum, bv, (float*)d_out);
}

// Round 6
// 91.367 us; speedup vs baseline: 1.7213x; 1.2590x over previous
//
#include <hip/hip_runtime.h>

#define HW   16384
#define CH   256
#define WD   128
#define NPTS 4

typedef _Float16 half8 __attribute__((ext_vector_type(8)));
typedef _Float16 half4 __attribute__((ext_vector_type(4)));
typedef float    f32x4 __attribute__((ext_vector_type(4)));

// ---- workspace layout (bytes) ----
#define WS_XT    0ull            // _Float16 [65536][256]  32 MB  (x transposed, per-pixel)
#define WS_WQK   33554432ull     // _Float16 [256][256]    128 KB (A = Wk^T Wq)
#define WS_WV    33685504ull     // _Float16 [256][256]    128 KB
#define WS_WOQ   33816576ull     // float    [256][8]      8 KB
#define WS_BOF   33824768ull     // float    [8] (64 B pad)
#define WS_CVEC  33824832ull     // float    [256]
#define WS_DVEC  33825856ull     // float    [256]
#define WS_SC    33826880ull     // float    [1] (64 B pad)
#define WS_SVEC  33826944ull     // float    [65536]  256 KB
#define WS_IDX   34089088ull     // int      [4][4][16384]  1 MB

// ---------- weight prep: A=Wk^T Wq fp16, cvec, Wv fp16, woq/bof, dvec, sconst ----------
__global__ void k_wprep(const float* __restrict__ Wq, const float* __restrict__ bq,
                        const float* __restrict__ Wk, const float* __restrict__ bk,
                        const float* __restrict__ Wv, const float* __restrict__ bv,
                        const float* __restrict__ Wo, const float* __restrict__ bo,
                        _Float16* __restrict__ wqk16, float* __restrict__ cvec,
                        _Float16* __restrict__ wv16, float* __restrict__ woq,
                        float* __restrict__ bof, float* __restrict__ dvec,
                        float* __restrict__ scst) {
    int bid = blockIdx.x, t = threadIdx.x;
    if (bid < 256) {                 // A[i][t] = sum_o Wk[o][i]*Wq[o][t]
        int i = bid;
        float s = 0.f;
        for (int o = 0; o < 256; o++) s += Wk[o * 256 + i] * Wq[o * 256 + t];
        wqk16[i * 256 + t] = (_Float16)s;
        if (t == 0) {
            float cs = 0.f;
            for (int o = 0; o < 256; o++) cs += Wk[o * 256 + i] * bq[o];
            cvec[i] = cs;
        }
    } else if (bid < 512) {          // Wv -> fp16
        int r = bid - 256;
        wv16[r * 256 + t] = (_Float16)Wv[r * 256 + t];
    } else if (bid < 520) {          // fused offset weights (fp32, discontinuous path)
        int j = bid - 512;
        float s = 0.f;
        for (int o = 0; o < 256; o++) s += Wo[j * 256 + o] * Wq[o * 256 + t];
        woq[t * 8 + j] = s;
        if (t == 0) {
            float tt = bo[j];
            for (int o = 0; o < 256; o++) tt += Wo[j * 256 + o] * bq[o];
            bof[j] = tt;
        }
    } else {                         // dvec[t] = sum_o bk[o]*Wq[o][t]; sconst = bq.bk
        float s = 0.f;
        for (int o = 0; o < 256; o++) s += bk[o] * Wq[o * 256 + t];
        dvec[t] = s;
        if (t == 0) {
            float sc = 0.f;
            for (int o = 0; o < 256; o++) sc += bq[o] * bk[o];
            scst[0] = sc;
        }
    }
}

// ---------- fused: x -> xt fp16, offsets -> idx (pure f32), s_p ----------
__launch_bounds__(256)
__global__ void k_prep(const float* __restrict__ x, const float* __restrict__ woq,
                       const float* __restrict__ bof, const float* __restrict__ dvec,
                       const float* __restrict__ scst,
                       _Float16* __restrict__ xt, int* __restrict__ idxb,
                       float* __restrict__ svec) {
    __shared__ float    wl[256 * 8];
    __shared__ float    dl[256];
    __shared__ float    bl8[8];
    __shared__ _Float16 tile[64][280];      // pitch 560B: b128 writes spread over all 8 slots
    __shared__ float    red[4][64][8];
    __shared__ float    reds[4][64];

    int t = threadIdx.x;
    for (int i = t; i < 256 * 8; i += 256) wl[i] = woq[i];
    dl[t] = dvec[t];
    if (t < 8) bl8[t] = bof[t];
    __syncthreads();

    int b = blockIdx.y;
    int p0 = blockIdx.x * 64;
    int pl = t & 63, cg = t >> 6;
    const float* xb = x + (size_t)b * CH * HW + p0 + pl;

    float acc[8];
    #pragma unroll
    for (int j = 0; j < 8; j++) acc[j] = 0.f;
    float accs = 0.f;

    for (int i0 = 0; i0 < 64; i0 += 8) {
        half8 hv;
        #pragma unroll
        for (int i = 0; i < 8; i++) {
            int c = cg * 64 + i0 + i;
            float xv = xb[(size_t)c * HW];
            hv[i] = (_Float16)xv;
            accs += dl[c] * xv;
            #pragma unroll
            for (int j = 0; j < 8; j++) acc[j] += wl[c * 8 + j] * xv;
        }
        *(half8*)(&tile[pl][cg * 64 + i0]) = hv;
    }
    #pragma unroll
    for (int j = 0; j < 8; j++) red[cg][pl][j] = acc[j];
    reds[cg][pl] = accs;
    __syncthreads();

    {
        int n = cg, p = p0 + pl;
        float sw_ = bl8[2 * n]     + red[0][pl][2 * n]     + red[1][pl][2 * n]
                                   + red[2][pl][2 * n]     + red[3][pl][2 * n];
        float sh_ = bl8[2 * n + 1] + red[0][pl][2 * n + 1] + red[1][pl][2 * n + 1]
                                   + red[2][pl][2 * n + 1] + red[3][pl][2 * n + 1];
        int h = p >> 7, w = p & 127;
        float rw = fminf(fmaxf((float)w + sw_, 0.f), 127.f);
        float rh = fminf(fmaxf((float)h + sh_, 0.f), 127.f);
        idxb[(b * NPTS + n) * HW + p] = ((int)rh) * WD + (int)rw;
        if (cg == 0)
            svec[b * HW + p] = reds[0][pl] + reds[1][pl] + reds[2][pl] + reds[3][pl] + scst[0];
    }

    {
        int row = t >> 2;
        size_t gbase = ((size_t)(b * HW + p0 + row)) * 256;
        #pragma unroll
        for (int s = 0; s < 8; s++) {
            int seg = (t & 3) + s * 4;
            *(uint4*)(xt + gbase + seg * 8) = *(const uint4*)(&tile[row][seg * 8]);
        }
    }
}

// ---------- fused GEMM1 + gather-attn + GEMM2 ----------
// block = 128 consecutive pixels (one image row), 256 thr, 80 KB LDS (2 blocks/CU).
// QW swizzle: half-index col' = col ^ ((row&7)<<3)  (16B-slot XOR within 8-row stripes)
__launch_bounds__(256)
__global__ void k_fused(const _Float16* __restrict__ xt, const _Float16* __restrict__ wqk16,
                        const _Float16* __restrict__ wv16, const float* __restrict__ cvec,
                        const float* __restrict__ bv, const int* __restrict__ idxb,
                        const float* __restrict__ svec, float* __restrict__ out) {
    __shared__ _Float16 QW[128 * 256];   // 64 KB: qh, then w (in place)
    __shared__ _Float16 As[128 * 32];    // 8 KB: phase-1 A staging; then asum (f32[128])
    __shared__ _Float16 Bs[128 * 32];    // 8 KB: B staging (wqk, then wv)

    int tid = threadIdx.x;
    int b = blockIdx.y;
    int bx = blockIdx.x;
    int logical = (bx & 7) * 16 + (bx >> 3);    // 128 = 8 XCD * 16, bijective
    int p0 = logical * 128;
    size_t mrow0 = (size_t)b * HW + p0;

    int lane = tid & 63, wid = tid >> 6;
    int wr = wid >> 1, wc = wid & 1;
    int g = lane >> 4, r = lane & 15;
    int ar = tid >> 2, aseg = tid & 3;
    int sw = aseg ^ ((ar >> 1) & 3);

    // ================= phase 1: qh = A.x + cvec -> QW =================
    for (int nh = 0; nh < 2; nh++) {
        f32x4 acc[4][4] = {};
        for (int kt = 0; kt < 8; kt++) {
            int k0 = kt * 32;
            uint4 a0 = *(const uint4*)(xt + (mrow0 + ar) * 256 + k0 + aseg * 8);
            uint4 a1 = *(const uint4*)(xt + (mrow0 + 64 + ar) * 256 + k0 + aseg * 8);
            uint4 b0 = *(const uint4*)(wqk16 + (size_t)(nh * 128 + ar) * 256 + k0 + aseg * 8);
            uint4 b1 = *(const uint4*)(wqk16 + (size_t)(nh * 128 + 64 + ar) * 256 + k0 + aseg * 8);
            __syncthreads();
            *(uint4*)(As + ar * 32 + sw * 8)        = a0;
            *(uint4*)(As + (64 + ar) * 32 + sw * 8) = a1;
            *(uint4*)(Bs + ar * 32 + sw * 8)        = b0;
            *(uint4*)(Bs + (64 + ar) * 32 + sw * 8) = b1;
            __syncthreads();

            half8 af[4], bf[4];
            #pragma unroll
            for (int mb = 0; mb < 4; mb++) {
                int row = wr * 64 + mb * 16 + r;
                int slot = g ^ ((row >> 1) & 3);
                af[mb] = *(const half8*)(As + row * 32 + slot * 8);
            }
            #pragma unroll
            for (int nb = 0; nb < 4; nb++) {
                int row = wc * 64 + nb * 16 + r;
                int slot = g ^ ((row >> 1) & 3);
                bf[nb] = *(const half8*)(Bs + row * 32 + slot * 8);
            }
            // swapped operands: D (g*4+reg) <- bf rows (n), (lane&15) <- af rows (m)
            #pragma unroll
            for (int mb = 0; mb < 4; mb++)
                #pragma unroll
                for (int nb = 0; nb < 4; nb++)
                    acc[mb][nb] = __builtin_amdgcn_mfma_f32_16x16x32_f16(bf[nb], af[mb], acc[mb][nb], 0, 0, 0);
        }
        // epilogue -> QW (swizzled), +cvec
        #pragma unroll
        for (int mb = 0; mb < 4; mb++) {
            int row = wr * 64 + mb * 16 + r;
            #pragma unroll
            for (int nb = 0; nb < 4; nb++) {
                int ncol = nh * 128 + wc * 64 + nb * 16 + g * 4;
                f32x4 cv = *(const f32x4*)(cvec + ncol);
                half4 h;
                #pragma unroll
                for (int i = 0; i < 4; i++) h[i] = (_Float16)(acc[mb][nb][i] + cv[i]);
                *(half4*)(&QW[(row << 8) + (ncol ^ ((row & 7) << 3))]) = h;
            }
        }
    }
    __syncthreads();

    // ================= phase 2: gather-attn, w overwrites qh in QW =================
    {
        float* asf = (float*)As;                 // As free now: asum[128]
        int seg = tid & 15, pslot = tid >> 4;    // 16 consecutive lanes = one pixel
        for (int it = 0; it < 8; it++) {
            int pl = it * 16 + pslot;
            size_t m = mrow0 + pl;
            int qa0 = (pl << 8) + ((seg * 16)     ^ ((pl & 7) << 3));
            int qa1 = (pl << 8) + ((seg * 16 + 8) ^ ((pl & 7) << 3));
            half8 q0 = *(const half8*)(&QW[qa0]);
            half8 q1 = *(const half8*)(&QW[qa1]);
            float sv = svec[m];
            int jj[NPTS];
            #pragma unroll
            for (int n = 0; n < NPTS; n++) jj[n] = idxb[(b * NPTS + n) * HW + p0 + pl];

            half8 xv[NPTS][2];
            #pragma unroll
            for (int n = 0; n < NPTS; n++) {
                const half8* xr = (const half8*)(xt + ((size_t)b * HW + jj[n]) * 256 + seg * 16);
                xv[n][0] = xr[0];
                xv[n][1] = xr[1];
            }
            float o[16];
            #pragma unroll
            for (int e = 0; e < 16; e++) o[e] = 0.f;
            float asl = 0.f;
            #pragma unroll
            for (int n = 0; n < NPTS; n++) {
                float d = 0.f;
                #pragma unroll
                for (int e = 0; e < 8; e++) d += (float)q0[e] * (float)xv[n][0][e];
                #pragma unroll
                for (int e = 0; e < 8; e++) d += (float)q1[e] * (float)xv[n][1][e];
                d += __shfl_xor(d, 1);
                d += __shfl_xor(d, 2);
                d += __shfl_xor(d, 4);
                d += __shfl_xor(d, 8);
                float a = d + sv;
                asl += a;
                #pragma unroll
                for (int e = 0; e < 8; e++) o[e]     += a * (float)xv[n][0][e];
                #pragma unroll
                for (int e = 0; e < 8; e++) o[8 + e] += a * (float)xv[n][1][e];
            }
            half8 h0, h1;
            #pragma unroll
            for (int e = 0; e < 8; e++) { h0[e] = (_Float16)o[e]; h1[e] = (_Float16)o[8 + e]; }
            *(half8*)(&QW[qa0]) = h0;            // same lane's own segment: no cross-lane hazard
            *(half8*)(&QW[qa1]) = h1;
            if (seg == 0) asf[pl] = asl;
        }
    }
    __syncthreads();

    // ================= phase 3: out = Wv.w + asum*bv =================
    {
        const float* asf = (const float*)As;
        for (int nh = 0; nh < 2; nh++) {
            f32x4 acc[4][4] = {};
            for (int kt = 0; kt < 8; kt++) {
                int k0 = kt * 32;
                uint4 b0 = *(const uint4*)(wv16 + (size_t)(nh * 128 + ar) * 256 + k0 + aseg * 8);
                uint4 b1 = *(const uint4*)(wv16 + (size_t)(nh * 128 + 64 + ar) * 256 + k0 + aseg * 8);
                __syncthreads();
                *(uint4*)(Bs + ar * 32 + sw * 8)        = b0;
                *(uint4*)(Bs + (64 + ar) * 32 + sw * 8) = b1;
                __syncthreads();

                half8 af[4], bf[4];
                #pragma unroll
                for (int mb = 0; mb < 4; mb++) {
                    int row = wr * 64 + mb * 16 + r;
                    af[mb] = *(const half8*)(&QW[(row << 8) + ((k0 + g * 8) ^ ((row & 7) << 3))]);
                }
                #pragma unroll
                for (int nb = 0; nb < 4; nb++) {
                    int row = wc * 64 + nb * 16 + r;
                    int slot = g ^ ((row >> 1) & 3);
                    bf[nb] = *(const half8*)(Bs + row * 32 + slot * 8);
                }
                #pragma unroll
                for (int mb = 0; mb < 4; mb++)
                    #pragma unroll
                    for (int nb = 0; nb < 4; nb++)
                        acc[mb][nb] = __builtin_amdgcn_mfma_f32_16x16x32_f16(bf[nb], af[mb], acc[mb][nb], 0, 0, 0);
            }
            #pragma unroll
            for (int mb = 0; mb < 4; mb++) {
                int mrow = wr * 64 + mb * 16 + r;
                float am = asf[mrow];
                float* obase = out + (size_t)b * CH * HW + p0 + mrow;
                #pragma unroll
                for (int nb = 0; nb < 4; nb++) {
                    int cb = nh * 128 + wc * 64 + nb * 16 + g * 4;
                    f32x4 bb = *(const f32x4*)(bv + cb);
                    #pragma unroll
                    for (int i = 0; i < 4; i++)
                        obase[(size_t)(cb + i) * HW] = acc[mb][nb][i] + am * bb[i];
                }
            }
        }
    }
}

extern "C" void kernel_launch(void* const* d_in, const int* in_sizes, int n_in,
                              void* d_out, int out_size, void* d_ws, size_t ws_size,
                              hipStream_t stream) {
    const float* x  = (const float*)d_in[0];
    const float* Wq = (const float*)d_in[1];
    const float* bq = (const float*)d_in[2];
    const float* Wk = (const float*)d_in[3];
    const float* bk = (const float*)d_in[4];
    const float* Wv = (const float*)d_in[5];
    const float* bv = (const float*)d_in[6];
    const float* Wo = (const float*)d_in[7];
    const float* bo = (const float*)d_in[8];
    (void)in_sizes; (void)n_in; (void)out_size; (void)ws_size;

    char* ws = (char*)d_ws;
    _Float16* xt    = (_Float16*)(ws + WS_XT);
    _Float16* wqk16 = (_Float16*)(ws + WS_WQK);
    _Float16* wv16  = (_Float16*)(ws + WS_WV);
    float*    woq   = (float*)(ws + WS_WOQ);
    float*    bof   = (float*)(ws + WS_BOF);
    float*    cvec  = (float*)(ws + WS_CVEC);
    float*    dvec  = (float*)(ws + WS_DVEC);
    float*    scst  = (float*)(ws + WS_SC);
    float*    svec  = (float*)(ws + WS_SVEC);
    int*      idxb  = (int*)(ws + WS_IDX);

    k_wprep<<<521, 256, 0, stream>>>(Wq, bq, Wk, bk, Wv, bv, Wo, bo,
                                     wqk16, cvec, wv16, woq, bof, dvec, scst);
    k_prep<<<dim3(256, 4), 256, 0, stream>>>(x, woq, bof, dvec, scst, xt, idxb, svec);
    k_fused<<<dim3(128, 4), 256, 0, stream>>>(xt, wqk16, wv16, cvec, bv, idxb, svec,
                                              (float*)d_out);
}